// Round 5
// baseline (77.425 us; speedup 1.0000x reference)
//
#include <hip/hip_runtime.h>

// Problem constants (match reference)
constexpr int Bn = 32;      // batch
constexpr int Nn = 512;     // logical qubits
constexpr int Qq = 512;     // physical qubits
constexpr int Ee = 4096;    // edges per batch
constexpr int Mtot = Bn * Nn;  // 16384 rows of P_flat

typedef short bf16x8 __attribute__((ext_vector_type(8)));
typedef float f32x4 __attribute__((ext_vector_type(4)));
typedef unsigned short u16;
typedef unsigned short u16x8 __attribute__((ext_vector_type(8)));

__device__ inline u16 f2bf(float f) {   // RNE float->bf16
    union { float f; unsigned u; } x; x.f = f;
    unsigned r = x.u + 0x7FFFu + ((x.u >> 16) & 1u);
    return (u16)(r >> 16);
}
__device__ inline float bf2f(u16 h) {
    union { unsigned u; float f; } x; x.u = ((unsigned)h) << 16;
    return x.f;
}
__device__ inline void gload_lds16(const u16* g, u16* l) {
    __builtin_amdgcn_global_load_lds(
        (const __attribute__((address_space(1))) unsigned int*)g,
        (__attribute__((address_space(3))) unsigned int*)l, 16, 0, 0);
}

// ---------------------------------------------------------------------------
// Kernel 1: inv_w[b] = 1/max(sum_e w, 1e-8); block 0 also zeroes out[0].
// ---------------------------------------------------------------------------
__global__ __launch_bounds__(256) void k_sumw(const float* __restrict__ edge_w,
                                              float* __restrict__ inv_w,
                                              float* __restrict__ out) {
    int b = blockIdx.x;
    const float* w = edge_w + (size_t)b * Ee;
    float s = 0.f;
    for (int i = threadIdx.x; i < Ee; i += 256) s += w[i];
    for (int off = 32; off; off >>= 1) s += __shfl_down(s, off);
    __shared__ float red[4];
    int wave = threadIdx.x >> 6, lane = threadIdx.x & 63;
    if (lane == 0) red[wave] = s;
    __syncthreads();
    if (threadIdx.x == 0) {
        float t = red[0] + red[1] + red[2] + red[3];
        inv_w[b] = 1.0f / fmaxf(t, 1e-8f);
        if (b == 0) out[0] = 0.f;
    }
}

// ---------------------------------------------------------------------------
// Kernel 2a: Dbf[q][r] = bf16( 3*max(d_hw-1,0) )
// ---------------------------------------------------------------------------
__global__ __launch_bounds__(256) void k_prep_d(const float* __restrict__ d_hw,
                                                u16* __restrict__ Dbf) {
    int i = blockIdx.x * 256 + threadIdx.x;   // 4 elems per thread
    float4 v = ((const float4*)d_hw)[i];
    ushort4 o;
    o.x = f2bf(3.f * fmaxf(v.x - 1.f, 0.f));
    o.y = f2bf(3.f * fmaxf(v.y - 1.f, 0.f));
    o.z = f2bf(3.f * fmaxf(v.z - 1.f, 0.f));
    o.w = f2bf(3.f * fmaxf(v.w - 1.f, 0.f));
    ((ushort4*)Dbf)[i] = o;
}

// ---------------------------------------------------------------------------
// Kernel 2b: Pbf = bf16(P)
// ---------------------------------------------------------------------------
__global__ __launch_bounds__(256) void k_prep_p(const float* __restrict__ P,
                                                u16* __restrict__ Pbf) {
    size_t i = (size_t)blockIdx.x * 256 + threadIdx.x;
    float4 v0 = ((const float4*)P)[i * 2];
    float4 v1 = ((const float4*)P)[i * 2 + 1];
    u16x8 o;
    o[0] = f2bf(v0.x); o[1] = f2bf(v0.y); o[2] = f2bf(v0.z); o[3] = f2bf(v0.w);
    o[4] = f2bf(v1.x); o[5] = f2bf(v1.y); o[6] = f2bf(v1.z); o[7] = f2bf(v1.w);
    ((u16x8*)Pbf)[i] = o;
}

// ---------------------------------------------------------------------------
// Kernel 3: C = A * B^T via MFMA 16x16x32 bf16.
//   BM=128, BN=64, BK=64; 2 waves/block (128 thr), each wave owns 64x64
//   (m97 per-wave sweet spot: 32 MFMA : 16 ds_read_b128 per K-iter).
//   Grid (512/64) x (16384/128) = 8 x 128 = 1024 wg; 24 KB LDS -> ~6 blk/CU.
//   LDS tiles are [row][64] bf16 (128 B rows). Bank-conflict fix per rule
//   #21: global_load_lds dest stays LINEAR; the GLOBAL source column-block
//   is pre-swizzled cb ^= (row&7), and ds_read uses the same XOR involution.
//   PER_BATCH=false: Bt = Dbf (symmetric)      -> G = P*D
//   PER_BATCH=true : Bt = Pbf + batch*512*512  -> S = G*P_b^T
// ---------------------------------------------------------------------------
template <bool PER_BATCH>
__global__ __launch_bounds__(128) void k_gemm(const u16* __restrict__ A,
                                              const u16* __restrict__ Bt,
                                              u16* __restrict__ C) {
    __shared__ u16 As[128 * 64];   // 16 KB
    __shared__ u16 Bs[64 * 64];    //  8 KB
    const int tid = threadIdx.x;          // 0..127
    const int lane = tid & 63;
    const int w = tid >> 6;               // wave 0/1: rows w*64..w*64+63
    const int M0 = blockIdx.y * 128, N0 = blockIdx.x * 64;

    // staging geometry: pass covers 16 rows x 64 shorts (2 KB). thread ->
    // (trow, tcb): row = p*16 + trow, colblock(16B) = tcb, global col is
    // inverse-swizzled: tcb ^ (row&7) == tcb ^ (trow&7)  (p*16 ≡ 0 mod 8).
    const int trow = tid >> 3;            // 0..15
    const int tcb = tid & 7;              // 0..7
    const int gcol = ((tcb ^ (trow & 7)) * 8);

    const u16* Bbase = PER_BATCH ? Bt + ((size_t)(blockIdx.y >> 2) * Nn * Qq) : Bt;
    const u16* gA = A + (size_t)(M0 + trow) * Qq + gcol;      // + p*16*512 + k0
    const u16* gB = Bbase + (size_t)(N0 + trow) * Qq + gcol;

    f32x4 acc[4][4] = {};

    for (int k0 = 0; k0 < Qq; k0 += 64) {
        #pragma unroll
        for (int p = 0; p < 8; ++p)
            gload_lds16(gA + (size_t)p * 16 * Qq + k0, As + p * 1024 + w * 512);
        #pragma unroll
        for (int p = 0; p < 4; ++p)
            gload_lds16(gB + (size_t)p * 16 * Qq + k0, Bs + p * 1024 + w * 512);
        __syncthreads();   // drains vmcnt

        bf16x8 a[2][4], b[2][4];
        #pragma unroll
        for (int kk = 0; kk < 2; ++kk) {
            #pragma unroll
            for (int mi = 0; mi < 4; ++mi) {
                int row = w * 64 + mi * 16 + (lane & 15);
                int cb = (kk * 4 + (lane >> 4)) ^ (row & 7);
                a[kk][mi] = *(const bf16x8*)&As[row * 64 + cb * 8];
            }
            #pragma unroll
            for (int ni = 0; ni < 4; ++ni) {
                int row = ni * 16 + (lane & 15);
                int cb = (kk * 4 + (lane >> 4)) ^ (row & 7);
                b[kk][ni] = *(const bf16x8*)&Bs[row * 64 + cb * 8];
            }
        }
        #pragma unroll
        for (int mi = 0; mi < 4; ++mi)
            #pragma unroll
            for (int ni = 0; ni < 4; ++ni) {
                acc[mi][ni] = __builtin_amdgcn_mfma_f32_16x16x32_bf16(a[0][mi], b[0][ni], acc[mi][ni], 0, 0, 0);
                acc[mi][ni] = __builtin_amdgcn_mfma_f32_16x16x32_bf16(a[1][mi], b[1][ni], acc[mi][ni], 0, 0, 0);
            }
        __syncthreads();
    }

    // epilogue: C/D layout col=lane&15, row=(lane>>4)*4+r  [guide m89]
    const int r0 = (lane >> 4) * 4;
    const int c = lane & 15;
    #pragma unroll
    for (int mi = 0; mi < 4; ++mi) {
        #pragma unroll
        for (int ni = 0; ni < 4; ++ni) {
            int row = M0 + w * 64 + mi * 16 + r0;
            int col = N0 + ni * 16 + c;
            #pragma unroll
            for (int r = 0; r < 4; ++r)
                C[(size_t)(row + r) * Qq + col] = f2bf(acc[mi][ni][r]);
        }
    }
}

// ---------------------------------------------------------------------------
// Kernel 4: out += sum_e w_e * S[b, src, dst] * inv_w[b] / B
// ---------------------------------------------------------------------------
__global__ __launch_bounds__(256) void k_lookup(const u16* __restrict__ S,
                                                const int* __restrict__ esrc,
                                                const int* __restrict__ edst,
                                                const float* __restrict__ ew,
                                                const float* __restrict__ inv_w,
                                                float* __restrict__ out) {
    int idx = blockIdx.x * 256 + threadIdx.x;   // 0 .. B*E-1
    int b = idx >> 12;                          // / 4096
    int s = esrc[idx];
    int d = edst[idx];
    float w = ew[idx] * inv_w[b];
    float val = bf2f(S[((size_t)b << 18) + ((size_t)s << 9) + (size_t)d]);
    float local = w * val;
    for (int off = 32; off; off >>= 1) local += __shfl_down(local, off);
    __shared__ float red[4];
    int wave = threadIdx.x >> 6, lane = threadIdx.x & 63;
    if (lane == 0) red[wave] = local;
    __syncthreads();
    if (threadIdx.x == 0)
        atomicAdd(out, (red[0] + red[1] + red[2] + red[3]) * (1.0f / Bn));
}

// ---------------------------------------------------------------------------
extern "C" void kernel_launch(void* const* d_in, const int* in_sizes, int n_in,
                              void* d_out, int out_size, void* d_ws, size_t ws_size,
                              hipStream_t stream) {
    const float* P    = (const float*)d_in[0];   // [B,N,Q] f32
    const float* d_hw = (const float*)d_in[1];   // [Q,Q]   f32
    const int* esrc   = (const int*)d_in[2];     // [B,E]
    const int* edst   = (const int*)d_in[3];     // [B,E]
    const float* ew   = (const float*)d_in[4];   // [B,E]
    float* out = (float*)d_out;

    char* ws = (char*)d_ws;
    float* inv_w = (float*)ws;                          // 32 f32 (1 KB reserved)
    u16* Pbf = (u16*)(ws + 1024);                       // [Mtot][512] bf16, 16.78 MB
    u16* Dbf = Pbf + (size_t)Mtot * Qq;                 // [512][512]  bf16, 0.52 MB
    u16* G   = Dbf + (size_t)Qq * Qq;                   // [Mtot][512] bf16, 16.78 MB
    u16* S   = G + (size_t)Mtot * Qq;                   // [B][512][512] bf16, 16.78 MB

    k_sumw<<<dim3(Bn), dim3(256), 0, stream>>>(ew, inv_w, out);
    k_prep_d<<<dim3(Qq * Qq / (4 * 256)), dim3(256), 0, stream>>>(d_hw, Dbf);
    k_prep_p<<<dim3((size_t)Mtot * Qq / (8 * 256)), dim3(256), 0, stream>>>(P, Pbf);
    k_gemm<false><<<dim3(Qq / 64, Mtot / 128), dim3(128), 0, stream>>>(Pbf, Dbf, G);
    k_gemm<true><<<dim3(Qq / 64, Mtot / 128), dim3(128), 0, stream>>>(G, Pbf, S);
    k_lookup<<<dim3((Bn * Ee) / 256), dim3(256), 0, stream>>>(
        S, esrc, edst, ew, inv_w, out);
}

// Round 6
// 57.816 us; speedup vs baseline: 1.3392x; 1.3392x over previous
//
#include <hip/hip_runtime.h>

// Problem constants (match reference)
constexpr int Bn = 32;      // batch
constexpr int Nn = 512;     // logical qubits
constexpr int Qq = 512;     // physical qubits
constexpr int Ee = 4096;    // edges per batch
constexpr int Mtot = Bn * Nn;  // 16384 rows of P_flat

typedef short bf16x8 __attribute__((ext_vector_type(8)));
typedef float f32x4 __attribute__((ext_vector_type(4)));
typedef unsigned short u16;
typedef unsigned short u16x8 __attribute__((ext_vector_type(8)));

__device__ inline u16 f2bf(float f) {   // RNE float->bf16
    union { float f; unsigned u; } x; x.f = f;
    unsigned r = x.u + 0x7FFFu + ((x.u >> 16) & 1u);
    return (u16)(r >> 16);
}
__device__ inline float bf2f(u16 h) {
    union { unsigned u; float f; } x; x.u = ((unsigned)h) << 16;
    return x.f;
}
__device__ inline void gload_lds16(const u16* g, u16* l) {
    __builtin_amdgcn_global_load_lds(
        (const __attribute__((address_space(1))) unsigned int*)g,
        (__attribute__((address_space(3))) unsigned int*)l, 16, 0, 0);
}

// ---------------------------------------------------------------------------
// Kernel 1: inv_w[b] = 1/max(sum_e w, 1e-8); block 0 also zeroes out[0].
// ---------------------------------------------------------------------------
__global__ __launch_bounds__(256) void k_sumw(const float* __restrict__ edge_w,
                                              float* __restrict__ inv_w,
                                              float* __restrict__ out) {
    int b = blockIdx.x;
    const float* w = edge_w + (size_t)b * Ee;
    float s = 0.f;
    for (int i = threadIdx.x; i < Ee; i += 256) s += w[i];
    for (int off = 32; off; off >>= 1) s += __shfl_down(s, off);
    __shared__ float red[4];
    int wave = threadIdx.x >> 6, lane = threadIdx.x & 63;
    if (lane == 0) red[wave] = s;
    __syncthreads();
    if (threadIdx.x == 0) {
        float t = red[0] + red[1] + red[2] + red[3];
        inv_w[b] = 1.0f / fmaxf(t, 1e-8f);
        if (b == 0) out[0] = 0.f;
    }
}

// ---------------------------------------------------------------------------
// Kernel 2a: Dbf[q][r] = bf16( 3*max(d_hw-1,0) )
// ---------------------------------------------------------------------------
__global__ __launch_bounds__(256) void k_prep_d(const float* __restrict__ d_hw,
                                                u16* __restrict__ Dbf) {
    int i = blockIdx.x * 256 + threadIdx.x;   // 4 elems per thread
    float4 v = ((const float4*)d_hw)[i];
    ushort4 o;
    o.x = f2bf(3.f * fmaxf(v.x - 1.f, 0.f));
    o.y = f2bf(3.f * fmaxf(v.y - 1.f, 0.f));
    o.z = f2bf(3.f * fmaxf(v.z - 1.f, 0.f));
    o.w = f2bf(3.f * fmaxf(v.w - 1.f, 0.f));
    ((ushort4*)Dbf)[i] = o;
}

// ---------------------------------------------------------------------------
// Kernel 2b: Pbf = bf16(P)
// ---------------------------------------------------------------------------
__global__ __launch_bounds__(256) void k_prep_p(const float* __restrict__ P,
                                                u16* __restrict__ Pbf) {
    size_t i = (size_t)blockIdx.x * 256 + threadIdx.x;
    float4 v0 = ((const float4*)P)[i * 2];
    float4 v1 = ((const float4*)P)[i * 2 + 1];
    u16x8 o;
    o[0] = f2bf(v0.x); o[1] = f2bf(v0.y); o[2] = f2bf(v0.z); o[3] = f2bf(v0.w);
    o[4] = f2bf(v1.x); o[5] = f2bf(v1.y); o[6] = f2bf(v1.z); o[7] = f2bf(v1.w);
    ((u16x8*)Pbf)[i] = o;
}

// ---------------------------------------------------------------------------
// Kernel 3: C = A * B^T via MFMA 16x16x32 bf16 — round-4 proven core:
//   BM=64, BN=128, BK=32, 256 thr (4 waves in 2x2; each wave 32x64, acc[2][4]).
//   1D grid + bijective XCD-chunk swizzle (T1): consecutive work-items that
//   share an A-panel land on the SAME XCD -> panel re-reads hit that L2.
//   PER_BATCH=false: G = P*D, 1024 tiles (t = y*4+x over [256]x[4]).
//   PER_BATCH=true : S = G*P_b^T, SYMMETRIC -> only 20 of 32 tiles per batch
//   (lower-triangle cover: mt >= 2*nt), 640 blocks total.
// ---------------------------------------------------------------------------
template <bool PER_BATCH>
__global__ __launch_bounds__(256) void k_gemm(const u16* __restrict__ A,
                                              const u16* __restrict__ Bt,
                                              u16* __restrict__ C) {
    __shared__ u16 As[64 * 32];    // 4 KB
    __shared__ u16 Bs[128 * 32];   // 8 KB
    const int tid = threadIdx.x;
    const int lane = tid & 63;
    const int wave = tid >> 6;
    const int wm = wave >> 1, wn = wave & 1;     // 2x2 waves over (64,128)

    // --- tile decode with XCD-chunk swizzle (bijective: nwg % 8 == 0) ---
    int M0, N0;                 // A-row base (global), B/C col base
    const u16* Bbase;
    u16* Crow;                  // C + M0*Qq
    if (!PER_BATCH) {
        int t = (blockIdx.x & 7) * 128 + (blockIdx.x >> 3);   // nwg=1024
        int xt = t & 3, yt = t >> 2;    // consecutive t share yt (A-panel)
        M0 = yt * 64; N0 = xt * 128;
        Bbase = Bt;
    } else {
        int t = (blockIdx.x % 8) * 80 + (blockIdx.x / 8);     // nwg=640
        int bb = t / 20, tt = t % 20;
        int nt = (tt < 8) ? 0 : (tt < 14) ? 1 : (tt < 18) ? 2 : 3;
        int mt = (tt < 8) ? tt : (tt < 14) ? tt - 6 : (tt < 18) ? tt - 10 : tt - 12;
        M0 = bb * 512 + mt * 64; N0 = nt * 128;
        Bbase = Bt + (size_t)bb * Nn * Qq;
    }
    Crow = C + (size_t)M0 * Qq;

    // staging: thread t covers linear bytes t*16 of a [rows][32] bf16 tile
    const int srow = tid >> 2;            // 0..63
    const int scol = (tid & 3) * 8;

    const u16* gA = A + (size_t)(M0 + srow) * Qq + scol;
    const u16* gB = Bbase + (size_t)(N0 + srow) * Qq + scol;

    u16* lA0 = As + wave * 512;
    u16* lB0 = Bs + wave * 512;           // rows 0..63
    u16* lB1 = Bs + 2048 + wave * 512;    // rows 64..127

    f32x4 acc[2][4] = {};

    for (int k0 = 0; k0 < Qq; k0 += 32) {
        gload_lds16(gA + k0, lA0);
        gload_lds16(gB + k0, lB0);
        gload_lds16(gB + (size_t)64 * Qq + k0, lB1);
        __syncthreads();   // drains vmcnt before barrier

        bf16x8 a[2], b[4];
        #pragma unroll
        for (int mi = 0; mi < 2; ++mi)
            a[mi] = *(const bf16x8*)&As[(wm * 32 + mi * 16 + (lane & 15)) * 32 + (lane >> 4) * 8];
        #pragma unroll
        for (int ni = 0; ni < 4; ++ni)
            b[ni] = *(const bf16x8*)&Bs[(wn * 64 + ni * 16 + (lane & 15)) * 32 + (lane >> 4) * 8];
        #pragma unroll
        for (int mi = 0; mi < 2; ++mi)
            #pragma unroll
            for (int ni = 0; ni < 4; ++ni)
                acc[mi][ni] = __builtin_amdgcn_mfma_f32_16x16x32_bf16(a[mi], b[ni], acc[mi][ni], 0, 0, 0);
        __syncthreads();
    }

    // epilogue: C/D layout col=lane&15, row=(lane>>4)*4+r  [guide m89]
    const int r0 = (lane >> 4) * 4;
    const int c = lane & 15;
    #pragma unroll
    for (int mi = 0; mi < 2; ++mi) {
        #pragma unroll
        for (int ni = 0; ni < 4; ++ni) {
            int row = wm * 32 + mi * 16 + r0;          // local within tile
            int col = N0 + wn * 64 + ni * 16 + c;
            #pragma unroll
            for (int r = 0; r < 4; ++r)
                Crow[(size_t)(row + r) * Qq + col] = f2bf(acc[mi][ni][r]);
        }
    }
}

// ---------------------------------------------------------------------------
// Kernel 4: out += sum_e w_e * S[b, max(s,d), min(s,d)] * inv_w[b] / B
//   (S is symmetric; only its lower triangle is materialized.)
// ---------------------------------------------------------------------------
__global__ __launch_bounds__(256) void k_lookup(const u16* __restrict__ S,
                                                const int* __restrict__ esrc,
                                                const int* __restrict__ edst,
                                                const float* __restrict__ ew,
                                                const float* __restrict__ inv_w,
                                                float* __restrict__ out) {
    int idx = blockIdx.x * 256 + threadIdx.x;   // 0 .. B*E-1
    int b = idx >> 12;                          // / 4096
    int s = esrc[idx];
    int d = edst[idx];
    int hi = max(s, d), lo = min(s, d);
    float w = ew[idx] * inv_w[b];
    float val = bf2f(S[((size_t)b << 18) + ((size_t)hi << 9) + (size_t)lo]);
    float local = w * val;
    for (int off = 32; off; off >>= 1) local += __shfl_down(local, off);
    __shared__ float red[4];
    int wave = threadIdx.x >> 6, lane = threadIdx.x & 63;
    if (lane == 0) red[wave] = local;
    __syncthreads();
    if (threadIdx.x == 0)
        atomicAdd(out, (red[0] + red[1] + red[2] + red[3]) * (1.0f / Bn));
}

// ---------------------------------------------------------------------------
extern "C" void kernel_launch(void* const* d_in, const int* in_sizes, int n_in,
                              void* d_out, int out_size, void* d_ws, size_t ws_size,
                              hipStream_t stream) {
    const float* P    = (const float*)d_in[0];   // [B,N,Q] f32
    const float* d_hw = (const float*)d_in[1];   // [Q,Q]   f32
    const int* esrc   = (const int*)d_in[2];     // [B,E]
    const int* edst   = (const int*)d_in[3];     // [B,E]
    const float* ew   = (const float*)d_in[4];   // [B,E]
    float* out = (float*)d_out;

    char* ws = (char*)d_ws;
    float* inv_w = (float*)ws;                          // 32 f32 (1 KB reserved)
    u16* Pbf = (u16*)(ws + 1024);                       // [Mtot][512] bf16, 16.78 MB
    u16* Dbf = Pbf + (size_t)Mtot * Qq;                 // [512][512]  bf16, 0.52 MB
    u16* G   = Dbf + (size_t)Qq * Qq;                   // [Mtot][512] bf16, 16.78 MB
    u16* S   = G + (size_t)Mtot * Qq;                   // [B][512][512] bf16, 16.78 MB

    k_sumw<<<dim3(Bn), dim3(256), 0, stream>>>(ew, inv_w, out);
    k_prep_d<<<dim3(Qq * Qq / (4 * 256)), dim3(256), 0, stream>>>(d_hw, Dbf);
    k_prep_p<<<dim3((size_t)Mtot * Qq / (8 * 256)), dim3(256), 0, stream>>>(P, Pbf);
    k_gemm<false><<<dim3(1024), dim3(256), 0, stream>>>(Pbf, Dbf, G);
    k_gemm<true><<<dim3(640), dim3(256), 0, stream>>>(G, Pbf, S);
    k_lookup<<<dim3((Bn * Ee) / 256), dim3(256), 0, stream>>>(
        S, esrc, edst, ew, inv_w, out);
}

// Round 7
// 52.810 us; speedup vs baseline: 1.4661x; 1.0948x over previous
//
#include <hip/hip_runtime.h>

// Problem constants (match reference)
constexpr int Bn = 32;      // batch
constexpr int Nn = 512;     // logical qubits
constexpr int Qq = 512;     // physical qubits
constexpr int Ee = 4096;    // edges per batch
constexpr int Mtot = Bn * Nn;  // 16384 rows of P_flat

typedef short bf16x8 __attribute__((ext_vector_type(8)));
typedef float f32x4 __attribute__((ext_vector_type(4)));
typedef unsigned short u16;
typedef unsigned short u16x8 __attribute__((ext_vector_type(8)));

__device__ inline u16 f2bf(float f) {   // RNE float->bf16
    union { float f; unsigned u; } x; x.f = f;
    unsigned r = x.u + 0x7FFFu + ((x.u >> 16) & 1u);
    return (u16)(r >> 16);
}
__device__ inline float bf2f(u16 h) {
    union { unsigned u; float f; } x; x.u = ((unsigned)h) << 16;
    return x.f;
}
__device__ inline void gload_lds16(const u16* g, u16* l) {
    __builtin_amdgcn_global_load_lds(
        (const __attribute__((address_space(1))) unsigned int*)g,
        (__attribute__((address_space(3))) unsigned int*)l, 16, 0, 0);
}

// ---------------------------------------------------------------------------
// Kernel 1 (merged): blocks 0..31  -> inv_w[b] (+ out[0]=0 on block 0)
//                    blocks 32..287 -> Dbf = bf16(3*max(d_hw-1,0))
// ---------------------------------------------------------------------------
__global__ __launch_bounds__(256) void k_init(const float* __restrict__ edge_w,
                                              const float* __restrict__ d_hw,
                                              float* __restrict__ inv_w,
                                              u16* __restrict__ Dbf,
                                              float* __restrict__ out) {
    if (blockIdx.x < 32) {
        int b = blockIdx.x;
        const float* w = edge_w + (size_t)b * Ee;
        float s = 0.f;
        for (int i = threadIdx.x; i < Ee; i += 256) s += w[i];
        for (int off = 32; off; off >>= 1) s += __shfl_down(s, off);
        __shared__ float red[4];
        int wave = threadIdx.x >> 6, lane = threadIdx.x & 63;
        if (lane == 0) red[wave] = s;
        __syncthreads();
        if (threadIdx.x == 0) {
            float t = red[0] + red[1] + red[2] + red[3];
            inv_w[b] = 1.0f / fmaxf(t, 1e-8f);
            if (b == 0) out[0] = 0.f;
        }
    } else {
        int i = (blockIdx.x - 32) * 256 + threadIdx.x;   // 4 elems per thread
        float4 v = ((const float4*)d_hw)[i];
        ushort4 o;
        o.x = f2bf(3.f * fmaxf(v.x - 1.f, 0.f));
        o.y = f2bf(3.f * fmaxf(v.y - 1.f, 0.f));
        o.z = f2bf(3.f * fmaxf(v.z - 1.f, 0.f));
        o.w = f2bf(3.f * fmaxf(v.w - 1.f, 0.f));
        ((ushort4*)Dbf)[i] = o;
    }
}

// ---------------------------------------------------------------------------
// Kernel 2: fused cast+GEMM1:  G = bf16(P) * D^T  (D symmetric).
//   Round-4 core: BM=64, BN=128, BK=32, 4 waves in 2x2, acc[2][4]/wave.
//   A is REG-STAGED from f32 P (global f32x8 -> f2bf -> ds_write_b128,
//   linear LDS layout identical to the gload_lds one). B (=Dbf) stays on
//   global_load_lds width-16. Blocks in the N0==0 column also store their
//   converted A-tile to Pbf (each P row covered exactly once) for GEMM2.
//   1D grid 1024 + bijective XCD-chunk swizzle (T1).
// ---------------------------------------------------------------------------
__global__ __launch_bounds__(256) void k_gemm1(const float* __restrict__ P,
                                               const u16* __restrict__ Dbf,
                                               u16* __restrict__ Pbf,
                                               u16* __restrict__ G) {
    __shared__ u16 As[64 * 32];    // 4 KB
    __shared__ u16 Bs[128 * 32];   // 8 KB
    const int tid = threadIdx.x;
    const int lane = tid & 63;
    const int wave = tid >> 6;
    const int wm = wave >> 1, wn = wave & 1;     // 2x2 waves over (64,128)

    // tile decode with XCD-chunk swizzle (nwg = 1024 = 8*128, bijective)
    int t = (blockIdx.x & 7) * 128 + (blockIdx.x >> 3);
    int xt = t & 3, yt = t >> 2;        // consecutive t share yt (A-panel)
    const int M0 = yt * 64, N0 = xt * 128;

    // staging geometry: thread t covers row srow, cols [scol, scol+8)
    const int srow = tid >> 2;            // 0..63
    const int scol = (tid & 3) * 8;

    const float* gA = P + (size_t)(M0 + srow) * Qq + scol;
    const u16* gB = Dbf + (size_t)(N0 + srow) * Qq + scol;
    u16* pOut = Pbf + (size_t)(M0 + srow) * Qq + scol;

    u16* lA = As + srow * 32 + scol;      // linear, = tid*16 bytes
    u16* lB0 = Bs + wave * 512;           // rows 0..63
    u16* lB1 = Bs + 2048 + wave * 512;    // rows 64..127

    f32x4 acc[2][4] = {};

    for (int k0 = 0; k0 < Qq; k0 += 32) {
        // B: async global->LDS
        gload_lds16(gB + k0, lB0);
        gload_lds16(gB + (size_t)64 * Qq + k0, lB1);
        // A: reg-stage f32 -> bf16 -> LDS
        float4 v0 = *(const float4*)(gA + k0);
        float4 v1 = *(const float4*)(gA + k0 + 4);
        u16x8 o;
        o[0] = f2bf(v0.x); o[1] = f2bf(v0.y); o[2] = f2bf(v0.z); o[3] = f2bf(v0.w);
        o[4] = f2bf(v1.x); o[5] = f2bf(v1.y); o[6] = f2bf(v1.z); o[7] = f2bf(v1.w);
        *(u16x8*)lA = o;
        if (N0 == 0) *(u16x8*)(pOut + k0) = o;   // publish bf16 P for GEMM2
        __syncthreads();   // drains vmcnt + lgkmcnt before fragment reads

        bf16x8 a[2], b[4];
        #pragma unroll
        for (int mi = 0; mi < 2; ++mi)
            a[mi] = *(const bf16x8*)&As[(wm * 32 + mi * 16 + (lane & 15)) * 32 + (lane >> 4) * 8];
        #pragma unroll
        for (int ni = 0; ni < 4; ++ni)
            b[ni] = *(const bf16x8*)&Bs[(wn * 64 + ni * 16 + (lane & 15)) * 32 + (lane >> 4) * 8];
        #pragma unroll
        for (int mi = 0; mi < 2; ++mi)
            #pragma unroll
            for (int ni = 0; ni < 4; ++ni)
                acc[mi][ni] = __builtin_amdgcn_mfma_f32_16x16x32_bf16(a[mi], b[ni], acc[mi][ni], 0, 0, 0);
        __syncthreads();
    }

    // epilogue: C/D layout col=lane&15, row=(lane>>4)*4+r  [guide m89]
    const int r0 = (lane >> 4) * 4;
    const int c = lane & 15;
    #pragma unroll
    for (int mi = 0; mi < 2; ++mi) {
        #pragma unroll
        for (int ni = 0; ni < 4; ++ni) {
            int row = M0 + wm * 32 + mi * 16 + r0;
            int col = N0 + wn * 64 + ni * 16 + c;
            #pragma unroll
            for (int r = 0; r < 4; ++r)
                G[(size_t)(row + r) * Qq + col] = f2bf(acc[mi][ni][r]);
        }
    }
}

// ---------------------------------------------------------------------------
// Kernel 3: GEMM2  S_b = G_b * P_b^T  (symmetric -> lower-triangle tiles only)
//   Round-4 core, both operands bf16 via global_load_lds. 640 blocks.
// ---------------------------------------------------------------------------
__global__ __launch_bounds__(256) void k_gemm2(const u16* __restrict__ A,
                                               const u16* __restrict__ Bt,
                                               u16* __restrict__ C) {
    __shared__ u16 As[64 * 32];    // 4 KB
    __shared__ u16 Bs[128 * 32];   // 8 KB
    const int tid = threadIdx.x;
    const int lane = tid & 63;
    const int wave = tid >> 6;
    const int wm = wave >> 1, wn = wave & 1;

    // tile decode with XCD-chunk swizzle (nwg = 640 = 8*80, bijective)
    int t = (blockIdx.x & 7) * 80 + (blockIdx.x >> 3);
    int bb = t / 20, tt = t % 20;
    int nt = (tt < 8) ? 0 : (tt < 14) ? 1 : (tt < 18) ? 2 : 3;
    int mt = (tt < 8) ? tt : (tt < 14) ? tt - 6 : (tt < 18) ? tt - 10 : tt - 12;
    const int M0 = bb * 512 + mt * 64, N0 = nt * 128;
    const u16* Bbase = Bt + (size_t)bb * Nn * Qq;

    const int srow = tid >> 2;
    const int scol = (tid & 3) * 8;

    const u16* gA = A + (size_t)(M0 + srow) * Qq + scol;
    const u16* gB = Bbase + (size_t)(N0 + srow) * Qq + scol;

    u16* lA0 = As + wave * 512;
    u16* lB0 = Bs + wave * 512;
    u16* lB1 = Bs + 2048 + wave * 512;

    f32x4 acc[2][4] = {};

    for (int k0 = 0; k0 < Qq; k0 += 32) {
        gload_lds16(gA + k0, lA0);
        gload_lds16(gB + k0, lB0);
        gload_lds16(gB + (size_t)64 * Qq + k0, lB1);
        __syncthreads();

        bf16x8 a[2], b[4];
        #pragma unroll
        for (int mi = 0; mi < 2; ++mi)
            a[mi] = *(const bf16x8*)&As[(wm * 32 + mi * 16 + (lane & 15)) * 32 + (lane >> 4) * 8];
        #pragma unroll
        for (int ni = 0; ni < 4; ++ni)
            b[ni] = *(const bf16x8*)&Bs[(wn * 64 + ni * 16 + (lane & 15)) * 32 + (lane >> 4) * 8];
        #pragma unroll
        for (int mi = 0; mi < 2; ++mi)
            #pragma unroll
            for (int ni = 0; ni < 4; ++ni)
                acc[mi][ni] = __builtin_amdgcn_mfma_f32_16x16x32_bf16(a[mi], b[ni], acc[mi][ni], 0, 0, 0);
        __syncthreads();
    }

    const int r0 = (lane >> 4) * 4;
    const int c = lane & 15;
    u16* Crow = C + (size_t)M0 * Qq;
    #pragma unroll
    for (int mi = 0; mi < 2; ++mi) {
        #pragma unroll
        for (int ni = 0; ni < 4; ++ni) {
            int row = wm * 32 + mi * 16 + r0;
            int col = N0 + wn * 64 + ni * 16 + c;
            #pragma unroll
            for (int r = 0; r < 4; ++r)
                Crow[(size_t)(row + r) * Qq + col] = f2bf(acc[mi][ni][r]);
        }
    }
}

// ---------------------------------------------------------------------------
// Kernel 4: out += sum_e w_e * S[b, max(s,d), min(s,d)] * inv_w[b] / B
// ---------------------------------------------------------------------------
__global__ __launch_bounds__(256) void k_lookup(const u16* __restrict__ S,
                                                const int* __restrict__ esrc,
                                                const int* __restrict__ edst,
                                                const float* __restrict__ ew,
                                                const float* __restrict__ inv_w,
                                                float* __restrict__ out) {
    int idx = blockIdx.x * 256 + threadIdx.x;   // 0 .. B*E-1
    int b = idx >> 12;                          // / 4096
    int s = esrc[idx];
    int d = edst[idx];
    int hi = max(s, d), lo = min(s, d);
    float w = ew[idx] * inv_w[b];
    float val = bf2f(S[((size_t)b << 18) + ((size_t)hi << 9) + (size_t)lo]);
    float local = w * val;
    for (int off = 32; off; off >>= 1) local += __shfl_down(local, off);
    __shared__ float red[4];
    int wave = threadIdx.x >> 6, lane = threadIdx.x & 63;
    if (lane == 0) red[wave] = local;
    __syncthreads();
    if (threadIdx.x == 0)
        atomicAdd(out, (red[0] + red[1] + red[2] + red[3]) * (1.0f / Bn));
}

// ---------------------------------------------------------------------------
extern "C" void kernel_launch(void* const* d_in, const int* in_sizes, int n_in,
                              void* d_out, int out_size, void* d_ws, size_t ws_size,
                              hipStream_t stream) {
    const float* P    = (const float*)d_in[0];   // [B,N,Q] f32
    const float* d_hw = (const float*)d_in[1];   // [Q,Q]   f32
    const int* esrc   = (const int*)d_in[2];     // [B,E]
    const int* edst   = (const int*)d_in[3];     // [B,E]
    const float* ew   = (const float*)d_in[4];   // [B,E]
    float* out = (float*)d_out;

    char* ws = (char*)d_ws;
    float* inv_w = (float*)ws;                          // 32 f32 (1 KB reserved)
    u16* Pbf = (u16*)(ws + 1024);                       // [Mtot][512] bf16, 16.78 MB
    u16* Dbf = Pbf + (size_t)Mtot * Qq;                 // [512][512]  bf16, 0.52 MB
    u16* G   = Dbf + (size_t)Qq * Qq;                   // [Mtot][512] bf16, 16.78 MB
    u16* S   = G + (size_t)Mtot * Qq;                   // [B][512][512] bf16, 16.78 MB

    k_init<<<dim3(32 + Qq * Qq / (4 * 256)), dim3(256), 0, stream>>>(
        ew, d_hw, inv_w, Dbf, out);
    k_gemm1<<<dim3(1024), dim3(256), 0, stream>>>(P, Dbf, Pbf, G);
    k_gemm2<<<dim3(640), dim3(256), 0, stream>>>(G, Pbf, S);
    k_lookup<<<dim3((Bn * Ee) / 256), dim3(256), 0, stream>>>(
        S, esrc, edst, ew, inv_w, out);
}